// Round 7
// baseline (627.866 us; speedup 1.0000x reference)
//
#include <hip/hip_runtime.h>
#include <hip/hip_bf16.h>

#define CDIM 384
#define NHEADS 12
#define HDIM 32
#define HIDDEN 1536
#define BBATCH 32
#define HH 28
#define WW 28
#define NTOK 784
#define BN (BBATCH * NTOK)   // 25088
#define LN_EPS 1e-5f
#define ATT_SCALE 0.17677669529663687f
#define YTILES 196           // BN / 128
#define PERXCD 25            // ceil(YTILES / 8)

typedef __hip_bfloat16 bf16;
typedef __attribute__((ext_vector_type(8))) short bf16x8;
typedef __attribute__((ext_vector_type(4))) float f32x4;

__device__ __forceinline__ float ldf(const float* p) { return *p; }
__device__ __forceinline__ float ldf(const bf16* p) { return __bfloat162float(*p); }
__device__ __forceinline__ void stf(float* p, float v) { *p = v; }
__device__ __forceinline__ void stf(bf16* p, float v) { *p = __float2bfloat16(v); }

__device__ __forceinline__ short f2bs(float v) {
    bf16 t = __float2bfloat16(v);
    return *reinterpret_cast<short*>(&t);
}

// tanh-form GELU via sigmoid; max |diff| vs exact ~3e-4, well inside tolerance.
__device__ __forceinline__ float gelu_f(float x) {
    float u = x * (0.7978845608f + 0.0356774081f * x * x);
    float e = __expf(-2.f * u);
    return x / (1.f + e);
}

__device__ __forceinline__ void gload16(const void* g, void* l) {
    __builtin_amdgcn_global_load_lds(
        (const __attribute__((address_space(1))) unsigned int*)g,
        (__attribute__((address_space(3))) unsigned int*)l, 16, 0, 0);
}

// ---------------- fp32 -> bf16 weight conversion (all 4 weights, one launch) ------------
__global__ __launch_bounds__(256) void f2b4_k(
    const float* __restrict__ w0, const float* __restrict__ w1,
    const float* __restrict__ w2, const float* __restrict__ w3,
    bf16* __restrict__ dst)
{
    int i = blockIdx.x * 256 + threadIdx.x;   // 0..1769471, dst regions contiguous
    const float* src; int off;
    if (i < 442368)       { src = w0; off = i; }
    else if (i < 589824)  { src = w1; off = i - 442368; }
    else if (i < 1179648) { src = w2; off = i - 589824; }
    else                  { src = w3; off = i - 1179648; }
    dst[i] = __float2bfloat16(src[off]);
}

// ---------------- transpose cpe2 weights (C,9) -> (9,C) ----------------
__global__ __launch_bounds__(256) void wtr_k(const float* __restrict__ w,
                                             float* __restrict__ wt)
{
    int i = blockIdx.x * 256 + threadIdx.x;   // 0..3455
    if (i < 9 * CDIM) {
        int k = i / CDIM, c = i % CDIM;
        wt[i] = w[c * 9 + k];
    }
}

// ---------------- dwconv1 pass A: per-(b,c) plane conv in NCHW, coalesced ----------------
__global__ __launch_bounds__(256) void dwconv_nchw_plane(
    const float* __restrict__ x, const float* __restrict__ w,
    const float* __restrict__ bias, float* __restrict__ y)
{
    __shared__ float sm[NTOK];
    int bc = blockIdx.x;                    // b*CDIM + c
    int c = bc % CDIM;
    const float* xp = x + (size_t)bc * NTOK;
    int tid = threadIdx.x;
#pragma unroll
    for (int i = 0; i < 4; i++) {
        int p = tid + i * 256;
        if (p < NTOK) sm[p] = xp[p];
    }
    __syncthreads();
    const float* wp = w + c * 9;
    float w00 = wp[0], w01 = wp[1], w02 = wp[2];
    float w10 = wp[3], w11 = wp[4], w12 = wp[5];
    float w20 = wp[6], w21 = wp[7], w22 = wp[8];
    float bc_ = bias[c];
    float* yp = y + (size_t)bc * NTOK;
#pragma unroll
    for (int i = 0; i < 4; i++) {
        int p = tid + i * 256;
        if (p >= NTOK) break;
        int h = p / WW, wcol = p % WW;
        bool hm = h > 0, hp = h < HH - 1, wm = wcol > 0, wpv = wcol < WW - 1;
        float s = w11 * sm[p];
        if (hm)        s += w01 * sm[p - WW];
        if (hp)        s += w21 * sm[p + WW];
        if (wm)        s += w10 * sm[p - 1];
        if (wpv)       s += w12 * sm[p + 1];
        if (hm && wm)  s += w00 * sm[p - WW - 1];
        if (hm && wpv) s += w02 * sm[p - WW + 1];
        if (hp && wm)  s += w20 * sm[p + WW - 1];
        if (hp && wpv) s += w22 * sm[p + WW + 1];
        yp[p] = sm[p] + s + bc_;
    }
}

// ---------------- dwconv1 pass B: transpose (B,C,N) -> (B,N,C) ----------------
__global__ __launch_bounds__(256) void transpose_in(
    const float* __restrict__ in, float* __restrict__ out)
{
    __shared__ float t[32][33];
    int b = blockIdx.z;
    int n0 = blockIdx.y * 32;
    int c0 = blockIdx.x * 32;
    int tx = threadIdx.x, ty = threadIdx.y;   // 32 x 8
    for (int i = ty; i < 32; i += 8) {
        int n = n0 + tx;
        if (n < NTOK) t[i][tx] = in[((size_t)b * CDIM + c0 + i) * NTOK + n];
    }
    __syncthreads();
    for (int i = ty; i < 32; i += 8) {
        int n = n0 + i;
        if (n < NTOK) out[((size_t)b * NTOK + n) * CDIM + c0 + tx] = t[tx][i];
    }
}

// ---------------- dwconv2 v2: (B,N,C) layout, float4 channels, XCD-contiguous swizzle ---
__global__ __launch_bounds__(256) void dwconv_bnc_v2(
    const float* __restrict__ xin, const float* __restrict__ wt,
    const float* __restrict__ bias, float* __restrict__ xout)
{
    const int nblk = (BN * 96) / 256;        // 9408
    const int per = nblk >> 3;               // 1176
    int blk = blockIdx.x;
    int blk2 = (blk & 7) * per + (blk >> 3);
    int g4 = blk2 * 256 + threadIdx.x;       // quad index: token*96 + c/4
    int q = g4 % 96;                         // c/4
    int r = g4 / 96;                         // b*NTOK + n
    int c = q * 4;
    int n = r % NTOK, b = r / NTOK;
    int h = n / WW, wcol = n % WW;
    const float4* base = (const float4*)(xin + (size_t)b * NTOK * CDIM);
    bool hm = h > 0, hp = h < HH - 1, wm = wcol > 0, wpv = wcol < WW - 1;

    float4 ctr = base[(size_t)n * 96 + q];
    float4 acc = {0.f, 0.f, 0.f, 0.f};

    const float4* w4 = (const float4*)wt;    // tap k at w4[k*96 + q]
#define TAP(k, cond, dn)                                            \
    if (cond) {                                                     \
        float4 vv = base[(size_t)(n + (dn)) * 96 + q];              \
        float4 ww = w4[(k) * 96 + q];                               \
        acc.x = fmaf(ww.x, vv.x, acc.x);                            \
        acc.y = fmaf(ww.y, vv.y, acc.y);                            \
        acc.z = fmaf(ww.z, vv.z, acc.z);                            \
        acc.w = fmaf(ww.w, vv.w, acc.w);                            \
    }
    TAP(0, hm && wm,   -WW - 1)
    TAP(1, hm,         -WW)
    TAP(2, hm && wpv,  -WW + 1)
    TAP(3, wm,         -1)
    { float4 ww = w4[4 * 96 + q];
      acc.x = fmaf(ww.x, ctr.x, acc.x); acc.y = fmaf(ww.y, ctr.y, acc.y);
      acc.z = fmaf(ww.z, ctr.z, acc.z); acc.w = fmaf(ww.w, ctr.w, acc.w); }
    TAP(5, wpv,        1)
    TAP(6, hp && wm,   WW - 1)
    TAP(7, hp,         WW)
    TAP(8, hp && wpv,  WW + 1)
#undef TAP
    float4 bb = *(const float4*)(bias + c);
    float4 outv;
    outv.x = ctr.x + acc.x + bb.x;
    outv.y = ctr.y + acc.y + bb.y;
    outv.z = ctr.z + acc.z + bb.z;
    outv.w = ctr.w + acc.w + bb.w;
    ((float4*)(xout))[g4] = outv;
}

// ---------------- LayerNorm over C=384, one wave per token; TO = float or bf16 ----------
template <typename TO>
__global__ __launch_bounds__(256) void layernorm_k(
    const float* __restrict__ in, const float* __restrict__ g,
    const float* __restrict__ b, TO* __restrict__ out)
{
    int wid = threadIdx.x >> 6;
    int lane = threadIdx.x & 63;
    size_t r = (size_t)blockIdx.x * 4 + wid;
    const float* row = in + r * CDIM;
    float v[6];
    float s = 0.f;
#pragma unroll
    for (int j = 0; j < 6; j++) { v[j] = row[lane + 64 * j]; s += v[j]; }
#pragma unroll
    for (int off = 32; off >= 1; off >>= 1) s += __shfl_xor(s, off);
    float mu = s * (1.f / CDIM);
    float q = 0.f;
#pragma unroll
    for (int j = 0; j < 6; j++) { float d = v[j] - mu; q += d * d; }
#pragma unroll
    for (int off = 32; off >= 1; off >>= 1) q += __shfl_xor(q, off);
    float rs = rsqrtf(q * (1.f / CDIM) + LN_EPS);
    TO* orow = out + r * CDIM;
#pragma unroll
    for (int j = 0; j < 6; j++) {
        int c = lane + 64 * j;
        stf(&orow[c], (v[j] - mu) * rs * g[c] + b[c]);
    }
}

// ---------------- MFMA GEMM v3 (qkv / proj): XCD panels + LDS double-buffer -----------
template <int ACT, bool RES, typename TO>
__global__ __launch_bounds__(256) void gemm_mfma(
    const short* __restrict__ Abf, const short* __restrict__ Bw,
    const float* __restrict__ bias, const float* __restrict__ res,
    TO* __restrict__ Co, int K, int M, int NX)
{
    int id = blockIdx.x;
    int xcd = id & 7, slot = id >> 3;
    int yloc = slot / NX, xx = slot - yloc * NX;
    int y = xcd * PERXCD + yloc;
    if (y >= YTILES) return;

    __shared__ short lds[32768];          // 64 KB: 2 x (As 8K | Bs 8K) shorts
    const int tid = threadIdx.x;
    const int wid = tid >> 6, lane = tid & 63;
    const int wrow = wid >> 1, wcol = wid & 1;
    const int quad = lane >> 4, lr = lane & 15;
    const int r0 = y * 128, m0 = xx * 128;

    const int srow = lane >> 3;
    const int sg   = (lane & 7) ^ srow;
    const short* gA = Abf + (size_t)(r0 + wid * 32 + srow) * K + sg * 8;
    const short* gB = Bw  + (size_t)(m0 + wid * 32 + srow) * K + sg * 8;

    auto stage = [&](int k0, int p) {
        short* lA = lds + p * 16384 + wid * 2048;
        short* lB = lds + p * 16384 + 8192 + wid * 2048;
#pragma unroll
        for (int k = 0; k < 4; k++) {
            gload16(gA + k0 + (size_t)k * 8 * K, lA + k * 512);
            gload16(gB + k0 + (size_t)k * 8 * K, lB + k * 512);
        }
    };

    int fAoff[4], fBoff[4];
#pragma unroll
    for (int i = 0; i < 4; i++) {
        fAoff[i] = (wrow * 64 + i * 16 + lr) * 64;
        fBoff[i] = (wcol * 64 + i * 16 + lr) * 64;
    }
    const int slot0 = ((0 + quad) ^ (lr & 7)) * 8;
    const int slot1 = ((4 + quad) ^ (lr & 7)) * 8;

    f32x4 acc[4][4] = {};

    stage(0, 0);
    int p = 0;
    for (int k0 = 0; k0 < K; k0 += 64) {
        __syncthreads();
        if (k0 + 64 < K) stage(k0 + 64, p ^ 1);
        const short* As = lds + p * 16384;
        const short* Bs = As + 8192;
#pragma unroll
        for (int s = 0; s < 2; s++) {
            const int so = s ? slot1 : slot0;
            bf16x8 av[4], bv[4];
#pragma unroll
            for (int i = 0; i < 4; i++) {
                av[i] = *(const bf16x8*)(As + fAoff[i] + so);
                bv[i] = *(const bf16x8*)(Bs + fBoff[i] + so);
            }
#pragma unroll
            for (int i = 0; i < 4; i++)
#pragma unroll
                for (int j = 0; j < 4; j++)
                    acc[i][j] = __builtin_amdgcn_mfma_f32_16x16x32_bf16(
                        av[i], bv[j], acc[i][j], 0, 0, 0);
        }
        p ^= 1;
    }

    if constexpr (sizeof(TO) == 4) {
#pragma unroll
        for (int i = 0; i < 4; i++) {
            int gr = r0 + wrow * 64 + i * 16 + quad * 4;
#pragma unroll
            for (int j = 0; j < 4; j++) {
                int gc = m0 + wcol * 64 + j * 16 + lr;
                float bb = bias ? bias[gc] : 0.f;
#pragma unroll
                for (int rr = 0; rr < 4; rr++) {
                    size_t idx = (size_t)(gr + rr) * M + gc;
                    float v = acc[i][j][rr] + bb;
                    if (RES) v += res[idx];
                    if (ACT == 1) v = gelu_f(v);
                    stf((float*)&Co[idx], v);
                }
            }
        }
    } else {
        __syncthreads();
        short* Cs = lds;
#pragma unroll
        for (int i = 0; i < 4; i++) {
            int lrow = wrow * 64 + i * 16 + quad * 4;
#pragma unroll
            for (int j = 0; j < 4; j++) {
                int lcol = wcol * 64 + j * 16 + lr;
                float bb = bias ? bias[m0 + lcol] : 0.f;
#pragma unroll
                for (int rr = 0; rr < 4; rr++) {
                    float v = acc[i][j][rr] + bb;
                    if (ACT == 1) v = gelu_f(v);
                    Cs[(lrow + rr) * 132 + lcol] = f2bs(v);
                }
            }
        }
        __syncthreads();
        short* co = (short*)Co;
#pragma unroll
        for (int s = 0; s < 16; s++) {
            int row = s * 8 + (tid >> 5);
            int seg = tid & 31;
            uint2 vv = *(const uint2*)(Cs + row * 132 + seg * 4);
            *(uint2*)(co + (size_t)(r0 + row) * M + m0 + seg * 4) = vv;
        }
    }
}

// ---------------- fused MLP: out = x3 + fc2(gelu(fc1(ylnb)))  -------------------------
// 196 blocks x 128 tokens; 4 waves, wave owns 32 rows (2 row-tiles of 16).
// h1 never hits HBM. LDS: conc staging (A|W1) dbuf 64 KB + H 34 KB + W2 quarters 51 KB
// = 149 KB (gfx950 LDS is 160 KB). 1 block/CU; __launch_bounds__(256,1) frees VGPRs.
__global__ __launch_bounds__(256, 1) void fused_mlp(
    const short* __restrict__ Xb,   // ylnb (BN x 384) bf16
    const short* __restrict__ W1,   // fc1_w (1536 x 384) bf16
    const short* __restrict__ W2,   // fc2_w (384 x 1536) bf16
    const float* __restrict__ b1, const float* __restrict__ b2,
    const float* __restrict__ res,  // x3 (BN x 384) fp32
    float* __restrict__ out)        // (BN x 384) fp32
{
    __shared__ short stagebuf[32768];      // 2 x 256 rows x 64 shorts (A rows | W1 rows)
    __shared__ short Hs[128 * 136];        // H tile, padded rows (per-wave private)
    __shared__ short W2s[2][96 * 136];     // W2 quarter chunks, padded, dbuf

    const int tid = threadIdx.x;
    const int wv = tid >> 6, lane = tid & 63;
    const int quad = lane >> 4, lr = lane & 15;
    const int r0 = blockIdx.x * 128;

    const int srow = lane >> 3;            // 0..7
    const int sg   = (lane & 7) ^ srow;    // XOR-granule swizzle (proven in gemm_mfma)

    int fA[2], fB[8];
#pragma unroll
    for (int i = 0; i < 2; i++) fA[i] = (wv * 32 + i * 16 + lr) * 64;
#pragma unroll
    for (int h = 0; h < 8; h++) fB[h] = (128 + h * 16 + lr) * 64;
    const int sl0 = (quad ^ (lr & 7)) * 8;
    const int sl1 = ((4 + quad) ^ (lr & 7)) * 8;

    f32x4 acc2[2][24] = {};                // 192 VGPR: fc2 accumulator (32 rows x 384)
    float4 w2reg[6];

    for (int m = 0; m < 12; m++) {
        // ---- fc1: acc1 = Xrows @ W1[m*128..+128, :]^T over K=384 ----
        f32x4 acc1[2][8] = {};
        auto stage_conc = [&](int k0, int p) {
            short* dst = stagebuf + p * 16384 + wv * 4096;
#pragma unroll
            for (int t = 0; t < 8; t++) {
                int cr = wv * 64 + t * 8 + srow;      // conc row 0..255
                const short* src = (cr < 128)
                    ? Xb + (size_t)(r0 + cr) * 384 + k0 + sg * 8
                    : W1 + (size_t)(m * 128 + cr - 128) * 384 + k0 + sg * 8;
                gload16(src, dst + t * 512);
            }
        };
        stage_conc(0, 0);
        int p = 0;
        for (int kit = 0; kit < 6; kit++) {
            __syncthreads();
            if (kit < 5) stage_conc((kit + 1) * 64, p ^ 1);
            const short* S = stagebuf + p * 16384;
#pragma unroll
            for (int sk = 0; sk < 2; sk++) {
                const int so = sk ? sl1 : sl0;
                bf16x8 av[2], bv[8];
#pragma unroll
                for (int i = 0; i < 2; i++) av[i] = *(const bf16x8*)(S + fA[i] + so);
#pragma unroll
                for (int h = 0; h < 8; h++) bv[h] = *(const bf16x8*)(S + fB[h] + so);
#pragma unroll
                for (int i = 0; i < 2; i++)
#pragma unroll
                    for (int h = 0; h < 8; h++)
                        acc1[i][h] = __builtin_amdgcn_mfma_f32_16x16x32_bf16(
                            av[i], bv[h], acc1[i][h], 0, 0, 0);
            }
            p ^= 1;
        }

        // ---- W2 quarter-0 loads (latency hidden under H epilogue) ----
        auto loadW2 = [&](int q) {
#pragma unroll
            for (int j = 0; j < 6; j++) {
                int f16i = j * 256 + tid;             // 16B unit within 24 KB quarter
                int row = f16i >> 4, g = f16i & 15;
                w2reg[j] = *(const float4*)(W2 + (size_t)(q * 96 + row) * 1536
                                            + m * 128 + g * 8);
            }
        };
        auto writeW2 = [&](int pq) {
#pragma unroll
            for (int j = 0; j < 6; j++) {
                int f16i = j * 256 + tid;
                int row = f16i >> 4, g = f16i & 15;
                *(float4*)(&W2s[pq][row * 136 + g * 8]) = w2reg[j];
            }
        };
        loadW2(0);

        // ---- H = gelu(acc1 + b1) -> per-wave-private LDS rows (no barrier needed) ----
#pragma unroll
        for (int i = 0; i < 2; i++)
#pragma unroll
            for (int h = 0; h < 8; h++) {
                int col = h * 16 + lr;
                float bb = b1[m * 128 + col];
#pragma unroll
                for (int rr = 0; rr < 4; rr++) {
                    float v = gelu_f(acc1[i][h][rr] + bb);
                    Hs[(wv * 32 + i * 16 + quad * 4 + rr) * 136 + col] = f2bs(v);
                }
            }
        writeW2(0);

        // ---- fc2: acc2 += H @ W2[:, m*128..+128]^T, quarters of 96 cols, dbuf ----
        for (int q = 0; q < 4; q++) {
            __syncthreads();                  // W2s[q&1] staged; prior reads drained
            if (q < 3) loadW2(q + 1);
#pragma unroll
            for (int kf = 0; kf < 4; kf++) {
                const int go = (kf * 4 + quad) * 8;
                bf16x8 ah[2], bw[6];
#pragma unroll
                for (int i = 0; i < 2; i++)
                    ah[i] = *(const bf16x8*)(&Hs[(wv * 32 + i * 16 + lr) * 136 + go]);
#pragma unroll
                for (int ct = 0; ct < 6; ct++)
                    bw[ct] = *(const bf16x8*)(&W2s[q & 1][(ct * 16 + lr) * 136 + go]);
#pragma unroll
                for (int i = 0; i < 2; i++)
#pragma unroll
                    for (int ct = 0; ct < 6; ct++)
                        acc2[i][q * 6 + ct] = __builtin_amdgcn_mfma_f32_16x16x32_bf16(
                            ah[i], bw[ct], acc2[i][q * 6 + ct], 0, 0, 0);
            }
            if (q < 3) writeW2((q + 1) & 1);
        }
    }

    // ---- epilogue: out = acc2 + b2 + res (fp32 full-line stores) ----
#pragma unroll
    for (int i = 0; i < 2; i++)
#pragma unroll
        for (int cti = 0; cti < 24; cti++) {
            int gc = cti * 16 + lr;
            float bb = b2[gc];
#pragma unroll
            for (int rr = 0; rr < 4; rr++) {
                size_t idx = (size_t)(r0 + wv * 32 + i * 16 + quad * 4 + rr) * 384 + gc;
                out[idx] = acc2[i][cti][rr] + bb + res[idx];
            }
        }
}

// ---------------- channel attention: attn[b,h,d,e] = softmax_e(SCALE * sum_n k*v) ------
__global__ __launch_bounds__(256) void attn_k(
    const bf16* __restrict__ qkv, float* __restrict__ attn)
{
    int bh = blockIdx.x;
    int b = bh / NHEADS, h = bh % NHEADS;
    __shared__ float ks[64][32];
    __shared__ float vs[64][32];
    __shared__ float sm[32][33];
    int tid = threadIdx.x;
    int d = tid >> 3, e0 = (tid & 7) * 4;
    float acc[4] = {0.f, 0.f, 0.f, 0.f};
    for (int n0 = 0; n0 < NTOK; n0 += 64) {
#pragma unroll
        for (int i = 0; i < 8; i++) {
            int idx = tid + i * 256;
            int nn = idx >> 5, cc = idx & 31;
            int n = n0 + nn;
            float kv = 0.f, vv = 0.f;
            if (n < NTOK) {
                size_t base = ((size_t)b * NTOK + n) * (3 * CDIM);
                kv = ATT_SCALE * __bfloat162float(qkv[base + CDIM + h * HDIM + cc]);
                vv = __bfloat162float(qkv[base + 2 * CDIM + h * HDIM + cc]);
            }
            ks[nn][cc] = kv; vs[nn][cc] = vv;
        }
        __syncthreads();
#pragma unroll 8
        for (int nn = 0; nn < 64; nn++) {
            float kd = ks[nn][d];
#pragma unroll
            for (int j = 0; j < 4; j++) acc[j] += kd * vs[nn][e0 + j];
        }
        __syncthreads();
    }
#pragma unroll
    for (int j = 0; j < 4; j++) sm[d][e0 + j] = acc[j];
    __syncthreads();
    if (tid < 32) {
        float mx = -1e30f;
#pragma unroll
        for (int e = 0; e < 32; e++) mx = fmaxf(mx, sm[tid][e]);
        float ssum = 0.f;
        float ex[32];
#pragma unroll
        for (int e = 0; e < 32; e++) { ex[e] = expf(sm[tid][e] - mx); ssum += ex[e]; }
        float inv = 1.f / ssum;
        float* arow = attn + ((size_t)bh * 32 + tid) * 32;
#pragma unroll
        for (int e = 0; e < 32; e++) arow[e] = ex[e] * inv;
    }
}

// ---------------- apply attention v2: attn row in registers, 8-token staged chunks -----
__global__ __launch_bounds__(384) void apply_attn_k(
    const bf16* __restrict__ qkv, const float* __restrict__ attn,
    bf16* __restrict__ out)
{
    int b = blockIdx.x;
    int chunk = blockIdx.y;            // 14 chunks of 56 tokens
    int tid = threadIdx.x;             // 0..383
    int h = tid >> 5;
    __shared__ float qs[8][CDIM];
    float at[32];
    const float4* ap = (const float4*)(attn + ((size_t)(b * NHEADS) * 32 + tid) * 32);
#pragma unroll
    for (int e4 = 0; e4 < 8; e4++) {
        float4 v = ap[e4];
        at[e4 * 4 + 0] = v.x; at[e4 * 4 + 1] = v.y;
        at[e4 * 4 + 2] = v.z; at[e4 * 4 + 3] = v.w;
    }
    int nbase = chunk * 56;
    for (int t0 = 0; t0 < 56; t0 += 8) {
        __syncthreads();
#pragma unroll
        for (int i = 0; i < 8; i++) {
            int n = nbase + t0 + i;
            qs[i][tid] = __bfloat162float(qkv[((size_t)b * NTOK + n) * (3 * CDIM) + tid]);
        }
        __syncthreads();
#pragma unroll
        for (int i = 0; i < 8; i++) {
            const float* qrow = &qs[i][h * 32];
            float s = 0.f;
#pragma unroll
            for (int e = 0; e < 32; e++) s += at[e] * qrow[e];
            int n = nbase + t0 + i;
            out[((size_t)b * NTOK + n) * CDIM + tid] = __float2bfloat16(s);
        }
    }
}

// ---------------- final transpose: (B,N,C) -> (B,C,H,W) ----------------
__global__ __launch_bounds__(256) void transpose_out(
    const float* __restrict__ in, float* __restrict__ out)
{
    __shared__ float t[32][33];
    int b = blockIdx.z;
    int n0 = blockIdx.y * 32;
    int c0 = blockIdx.x * 32;
    int tx = threadIdx.x, ty = threadIdx.y;   // 32 x 8
    for (int i = ty; i < 32; i += 8) {
        int n = n0 + i;
        if (n < NTOK) t[i][tx] = in[((size_t)b * NTOK + n) * CDIM + c0 + tx];
    }
    __syncthreads();
    for (int i = ty; i < 32; i += 8) {
        int c = c0 + i;
        int n = n0 + tx;
        if (n < NTOK) out[((size_t)b * CDIM + c) * NTOK + n] = t[tx][i];
    }
}

extern "C" void kernel_launch(void* const* d_in, const int* in_sizes, int n_in,
                              void* d_out, int out_size, void* d_ws, size_t ws_size,
                              hipStream_t stream) {
    const float* x      = (const float*)d_in[0];
    const float* cpe1_w = (const float*)d_in[1];
    const float* cpe1_b = (const float*)d_in[2];
    const float* n1g    = (const float*)d_in[3];
    const float* n1b    = (const float*)d_in[4];
    const float* qkv_w  = (const float*)d_in[5];
    const float* proj_w = (const float*)d_in[6];
    const float* proj_b = (const float*)d_in[7];
    const float* cpe2_w = (const float*)d_in[8];
    const float* cpe2_b = (const float*)d_in[9];
    const float* n2g    = (const float*)d_in[10];
    const float* n2b    = (const float*)d_in[11];
    const float* fc1_w  = (const float*)d_in[12];
    const float* fc1_b  = (const float*)d_in[13];
    const float* fc2_w  = (const float*)d_in[14];
    const float* fc2_b  = (const float*)d_in[15];

    const size_t A = (size_t)BN * CDIM;        // 9,633,792
    const size_t HA = A / 2;

    // bf16 weights contiguous at front of ws
    bf16* wqkv  = (bf16*)d_ws;                 // 442368
    bf16* wproj = wqkv + 442368;               // 147456
    bf16* wfc1  = wproj + 147456;              // 589824
    bf16* wfc2  = wfc1 + 589824;               // 589824
    float* base = (float*)d_ws + 884736;

    float* xt        = base;                   // [0, A)        residual stream
    bf16*  curb      = (bf16*)(base + A);      // [A, 1.5A)     LN1 out (bf16)
    bf16*  ylnb      = (bf16*)(base + A);      // phase-2 reuse LN2 out (bf16)
    bf16*  qkvb      = (bf16*)(base + A + HA); // [1.5A, 3A)    qkv (bf16, 3A elems)
    float* x3        = base + A + HA;          // phase-2 reuse [1.5A, 2.5A)
    float* attnm     = base + 3 * A;           // [3A, +393216)
    bf16*  attn_outb = (bf16*)(base + 3 * A + 393216);
    float* finalb    = base;                   // xt region reuse
    float* xconv     = base + (A * 7) / 2;     // [3.5A, 4.5A)  dwconv1 NCHW temp
    float* cpe2_wt   = base + (A * 9) / 2;     // [4.5A, +3456) transposed taps

    const int GEMM_GRID3  = 8 * PERXCD * 3;    // 600
    const int GEMM_GRID9  = 8 * PERXCD * 9;    // 1800

    // 0. weight conversion fp32 -> bf16 (single launch) + cpe2 tap transpose
    f2b4_k<<<1769472 / 256, 256, 0, stream>>>(qkv_w, proj_w, fc1_w, fc2_w, wqkv);
    wtr_k<<<14, 256, 0, stream>>>(cpe2_w, cpe2_wt);

    // 1a. cpe1 + residual in NCHW (coalesced, LDS-planed)
    dwconv_nchw_plane<<<BBATCH * CDIM, 256, 0, stream>>>(x, cpe1_w, cpe1_b, xconv);
    // 1b. transpose (B,C,N) -> (B,N,C)
    transpose_in<<<dim3(CDIM / 32, (NTOK + 31) / 32, BBATCH), dim3(32, 8), 0, stream>>>(
        xconv, xt);
    // 2. LN1 -> bf16
    layernorm_k<bf16><<<BN / 4, 256, 0, stream>>>(xt, n1g, n1b, curb);
    // 3. qkv GEMM (bf16 MFMA, out bf16)
    gemm_mfma<0, false, bf16><<<GEMM_GRID9, 256, 0, stream>>>(
        (const short*)curb, (const short*)wqkv, nullptr, nullptr, qkvb, 384, 1152, 9);
    // 4. channel attention matrices + softmax
    attn_k<<<BBATCH * NHEADS, 256, 0, stream>>>(qkvb, attnm);
    // 5. apply attention to q (out bf16)
    apply_attn_k<<<dim3(BBATCH, 14), 384, 0, stream>>>(qkvb, attnm, attn_outb);
    // 6. proj GEMM + bias + residual (in-place into xt)
    gemm_mfma<0, true, float><<<GEMM_GRID3, 256, 0, stream>>>(
        (const short*)attn_outb, (const short*)wproj, proj_b, xt, xt, 384, 384, 3);
    // 7. cpe2 + residual in (B,N,C)  — XCD-swizzled, float4
    dwconv_bnc_v2<<<(BN * 96) / 256, 256, 0, stream>>>(xt, cpe2_wt, cpe2_b, x3);
    // 8. LN2 -> bf16
    layernorm_k<bf16><<<BN / 4, 256, 0, stream>>>(x3, n2g, n2b, ylnb);
    // 9+10. fused MLP: finalb = x3 + fc2(gelu(fc1(ylnb)))
    fused_mlp<<<YTILES, 256, 0, stream>>>(
        (const short*)ylnb, (const short*)wfc1, (const short*)wfc2,
        fc1_b, fc2_b, x3, finalb);
    // 11. (B,N,C) -> (B,C,H,W)
    transpose_out<<<dim3(CDIM / 32, (NTOK + 31) / 32, BBATCH), dim3(32, 8), 0, stream>>>(
        finalb, (float*)d_out);
}